// Round 3
// baseline (492.025 us; speedup 1.0000x reference)
//
#include <hip/hip_runtime.h>

// GaborAutoencoder on MI355X (gfx950)
// split fp32 -> fp16 (hi, lo*4096) -> 3-pass split-precision MFMA GEMMs -> Gabor synth.
// R2: fragment-order LDS layout (stride-1 ds_read_b128, zero bank conflicts),
//     TM=64 tile variant for small GEMMs (2 blocks/CU), merged split kernels.
// R3: fix vector-element reference compile error (split_one returns by value).

#define SIGNAL_LEN 2048
#define NWAV 32

typedef _Float16 f16x8 __attribute__((ext_vector_type(8)));
typedef _Float16 f16x4 __attribute__((ext_vector_type(4)));
typedef float    f32x4 __attribute__((ext_vector_type(4)));

__device__ __forceinline__ void load16_lds(const _Float16* g, _Float16* l) {
  __builtin_amdgcn_global_load_lds((const __attribute__((address_space(1))) void*)g,
                                   (__attribute__((address_space(3))) void*)l,
                                   16, 0, 0);
}

struct HL { _Float16 h, l; };
__device__ __forceinline__ HL split_one(float a) {
  HL r;
  r.h = (_Float16)a;
  r.l = (_Float16)((a - (float)r.h) * 4096.0f);
  return r;
}

// ---------------------------------------------------------------------------
// X split: fp32 float4 -> hi/lo f16x4
// ---------------------------------------------------------------------------
__global__ void split_x(const float4* __restrict__ src, f16x4* __restrict__ dh,
                        f16x4* __restrict__ dl) {
  int i = blockIdx.x * 256 + threadIdx.x;  // 4194304 float4s
  float4 v = src[i];
  float a[4] = {v.x, v.y, v.z, v.w};
  f16x4 h, l;
#pragma unroll
  for (int j = 0; j < 4; j++) {
    HL r = split_one(a[j]);
    h[j] = r.h;
    l[j] = r.l;
  }
  dh[i] = h;
  dl[i] = l;
}

// ---------------------------------------------------------------------------
// all weight splits in one launch (scaled x256); W4 padded 160x256 -> 256x256
// blocks: [0,4096) W1 | [4096,4608) W2 | [4608,4736) W3 | [4736,4800) W4 | 4800 b4
// ---------------------------------------------------------------------------
__global__ void split_weights(const float* __restrict__ W1, const float* __restrict__ W2,
                              const float* __restrict__ W3, const float* __restrict__ W4,
                              const float* __restrict__ b4,
                              f16x4* __restrict__ W1h, f16x4* __restrict__ W1l,
                              f16x4* __restrict__ W2h, f16x4* __restrict__ W2l,
                              f16x4* __restrict__ W3h, f16x4* __restrict__ W3l,
                              f16x4* __restrict__ W4h, f16x4* __restrict__ W4l,
                              float* __restrict__ b4p) {
  const int blk = blockIdx.x;
  const int tid = threadIdx.x;
  if (blk < 4736) {
    const float4* src;
    f16x4 *dh, *dl;
    int i;
    if (blk < 4096) {
      src = (const float4*)W1; dh = W1h; dl = W1l; i = blk * 256 + tid;
    } else if (blk < 4608) {
      src = (const float4*)W2; dh = W2h; dl = W2l; i = (blk - 4096) * 256 + tid;
    } else {
      src = (const float4*)W3; dh = W3h; dl = W3l; i = (blk - 4608) * 256 + tid;
    }
    float4 v = src[i];
    float a[4] = {v.x * 256.0f, v.y * 256.0f, v.z * 256.0f, v.w * 256.0f};
    f16x4 h, l;
#pragma unroll
    for (int j = 0; j < 4; j++) {
      HL r = split_one(a[j]);
      h[j] = r.h;
      l[j] = r.l;
    }
    dh[i] = h;
    dl[i] = l;
  } else if (blk < 4800) {
    int i = (blk - 4736) * 256 + tid;  // 16384 f16x4 outputs over 256x256
    int i4 = i << 2;
    int row = i4 >> 8;
    f16x4 h, l;
#pragma unroll
    for (int j = 0; j < 4; j++) {
      float a = (row < 160) ? W4[i4 + j] * 256.0f : 0.0f;
      HL r = split_one(a);
      h[j] = r.h;
      l[j] = r.l;
    }
    W4h[i] = h;
    W4l[i] = l;
  } else {
    b4p[tid] = (tid < 160) ? b4[tid] : 0.0f;
  }
}

// ---------------------------------------------------------------------------
// fp16x2 split-precision GEMM: C[M,N] = A[M,K]*B[N,K]^T (+bias, relu)
// tile TM(M) x 64(N), BK=32, 256 threads = 4 waves 2x2, 16x16x32 MFMA.
// LDS in FRAGMENT ORDER: chunk group g (16 rows x 8 halves of k) at g*1024 B,
// so every ds_read_b128 is base + lane*16 (stride-1, conflict-free) and every
// global_load_lds dst is wave-uniform base + lane*16.
// ---------------------------------------------------------------------------
template <int TM, int N, int K, bool RELU, bool SPLIT_OUT>
__global__ void __launch_bounds__(256, 2)
gemm_f16x2(const _Float16* __restrict__ Ah, const _Float16* __restrict__ Al,
           const _Float16* __restrict__ Bh, const _Float16* __restrict__ Bl,
           const float* __restrict__ bias,
           _Float16* __restrict__ Ch, _Float16* __restrict__ Cl,
           float* __restrict__ Cf) {
  constexpr int IM = TM / 32;  // A fragments per wave in m
  __shared__ __align__(16) _Float16 sAh[TM * 32];
  __shared__ __align__(16) _Float16 sAl[TM * 32];
  __shared__ __align__(16) _Float16 sBh[64 * 32];
  __shared__ __align__(16) _Float16 sBl[64 * 32];

  const int tid = threadIdx.x;
  const int lane = tid & 63;
  const int w = tid >> 6;
  const int wm = w >> 1, wn = w & 1;
  const int m0 = blockIdx.y * TM;
  const int n0 = blockIdx.x * 64;

  // staging: lane = kc*16 + fr stages global (row = 16w+fr, k8 = kc*8) into
  // LDS slot (w*64 + lane)  ==> fragment-order layout
  const int fr = lane & 15;
  const int kc = lane >> 4;

  const size_t aOff = (size_t)(m0 + 16 * w + fr) * K + kc * 8;
  const _Float16* gAh0 = Ah + aOff;
  const _Float16* gAl0 = Al + aOff;
  const size_t bOff = (size_t)(n0 + 16 * w + fr) * K + kc * 8;
  const _Float16* gBh0 = Bh + bOff;
  const _Float16* gBl0 = Bl + bOff;

  _Float16* lAh0 = sAh + w * 512;
  _Float16* lAl0 = sAl + w * 512;
  _Float16* lAh1 = sAh + 2048 + w * 512;  // rows 64..127 (TM=128 only)
  _Float16* lAl1 = sAl + 2048 + w * 512;
  _Float16* lBh = sBh + w * 512;
  _Float16* lBl = sBl + w * 512;

  f32x4 acc1[IM][2], acc2[IM][2];
#pragma unroll
  for (int i = 0; i < IM; i++)
#pragma unroll
    for (int j = 0; j < 2; j++) {
      acc1[i][j] = 0.0f;
      acc2[i][j] = 0.0f;
    }

  for (int kt = 0; kt < K; kt += 32) {
    load16_lds(gAh0 + kt, lAh0);
    load16_lds(gAl0 + kt, lAl0);
    if (TM == 128) {
      load16_lds(gAh0 + (size_t)64 * K + kt, lAh1);
      load16_lds(gAl0 + (size_t)64 * K + kt, lAl1);
    }
    load16_lds(gBh0 + kt, lBh);
    load16_lds(gBl0 + kt, lBl);
    __syncthreads();

    // fragment reads: group g at g*512 halves, contiguous lane*8
    f16x8 fAh[IM], fAl[IM], fBh[2], fBl[2];
#pragma unroll
    for (int im = 0; im < IM; im++) {
      fAh[im] = *(const f16x8*)(sAh + (wm * IM + im) * 512 + lane * 8);
      fAl[im] = *(const f16x8*)(sAl + (wm * IM + im) * 512 + lane * 8);
    }
#pragma unroll
    for (int in = 0; in < 2; in++) {
      fBh[in] = *(const f16x8*)(sBh + (wn * 2 + in) * 512 + lane * 8);
      fBl[in] = *(const f16x8*)(sBl + (wn * 2 + in) * 512 + lane * 8);
    }
#pragma unroll
    for (int im = 0; im < IM; im++) {
#pragma unroll
      for (int in = 0; in < 2; in++) {
        acc1[im][in] = __builtin_amdgcn_mfma_f32_16x16x32_f16(fAh[im], fBh[in], acc1[im][in], 0, 0, 0);
        acc2[im][in] = __builtin_amdgcn_mfma_f32_16x16x32_f16(fAh[im], fBl[in], acc2[im][in], 0, 0, 0);
        acc2[im][in] = __builtin_amdgcn_mfma_f32_16x16x32_f16(fAl[im], fBh[in], acc2[im][in], 0, 0, 0);
      }
    }
    __syncthreads();
  }

  // epilogue: C/D layout col=lane&15, row=quad*4+reg
  const int quad = lane >> 4;
#pragma unroll
  for (int in = 0; in < 2; in++) {
    const int n = n0 + wn * 32 + in * 16 + fr;
    const float bv = bias[n];
#pragma unroll
    for (int im = 0; im < IM; im++) {
#pragma unroll
      for (int r = 0; r < 4; r++) {
        const int m = m0 + wm * (TM / 2) + im * 16 + quad * 4 + r;
        float c = (acc1[im][in][r] + acc2[im][in][r] * (1.0f / 4096.0f)) * (1.0f / 256.0f) + bv;
        if (RELU) c = fmaxf(c, 0.0f);
        const size_t off = (size_t)m * N + n;
        if (SPLIT_OUT) {
          HL rr = split_one(c);
          Ch[off] = rr.h;
          Cl[off] = rr.l;
        } else {
          Cf[off] = c;
        }
      }
    }
  }
}

// ---------------------------------------------------------------------------
// Gabor synthesis: one block per batch, 256 threads x 8 t-samples each
// ---------------------------------------------------------------------------
__global__ void __launch_bounds__(256)
synth(const float* __restrict__ P, float* __restrict__ out) {
  __shared__ float sA[NWAV], sT0[NWAV], sF[NWAV], sC[NWAV], sPh[NWAV];
  const int b = blockIdx.x;
  const int tid = threadIdx.x;
  if (tid < NWAV) {
    const float* q = P + (size_t)b * 256 + tid * 5;
    const float L2E = 1.44269504088896340736f;
    float A = q[0], p1 = q[1], p2 = q[2], p3 = q[3], p4 = q[4];
    float s1 = 1.0f / (1.0f + exp2f(-p1 * L2E));
    float s2 = 1.0f / (1.0f + exp2f(-p2 * L2E));
    float s3 = 1.0f / (1.0f + exp2f(-p3 * L2E));
    float sg = s3 * 200.0f + 2.0f;
    sA[tid] = A;
    sT0[tid] = s1 * 2048.0f;
    sF[tid] = s2 * 0.5f;
    sC[tid] = -L2E / (2.0f * sg * sg);          // exp(-dt^2/(2s^2)) = exp2(dt^2*sC)
    sPh[tid] = p4 * 0.15915494309189535f;       // phi in revolutions
  }
  __syncthreads();

  float acc[8];
  float tv[8];
#pragma unroll
  for (int i = 0; i < 8; i++) {
    acc[i] = 0.0f;
    tv[i] = (float)(tid + i * 256);
  }

  for (int wv = 0; wv < NWAV; wv++) {
    const float A = sA[wv], t0 = sT0[wv], fr = sF[wv], cn = sC[wv], ph = sPh[wv];
#pragma unroll
    for (int i = 0; i < 8; i++) {
      float dt = tv[i] - t0;
      float e = exp2f(dt * dt * cn);
      float r = fr * dt + ph;                    // phase in revolutions
      r -= floorf(r);                            // reduce to [0,1)
      float cs = __builtin_amdgcn_cosf(r);       // v_cos_f32: cos(2*pi*r)
      acc[i] += A * e * cs;
    }
  }

  float* o = out + (size_t)b * (2 * SIGNAL_LEN);
#pragma unroll
  for (int i = 0; i < 8; i++) {
    o[tid + i * 256] = acc[i];
    o[SIGNAL_LEN + tid + i * 256] = acc[i];      // both channels identical
  }
}

// ---------------------------------------------------------------------------
extern "C" void kernel_launch(void* const* d_in, const int* in_sizes, int n_in,
                              void* d_out, int out_size, void* d_ws, size_t ws_size,
                              hipStream_t stream) {
  (void)in_sizes; (void)n_in; (void)out_size; (void)ws_size;
  const float* X  = (const float*)d_in[0];
  const float* W1 = (const float*)d_in[1];
  const float* b1 = (const float*)d_in[2];
  const float* W2 = (const float*)d_in[3];
  const float* b2 = (const float*)d_in[4];
  const float* W3 = (const float*)d_in[5];
  const float* b3 = (const float*)d_in[6];
  const float* W4 = (const float*)d_in[7];
  const float* b4 = (const float*)d_in[8];
  float* out = (float*)d_out;

  char* p = (char*)d_ws;
  auto take = [&](size_t bytes) -> char* {
    char* r = p;
    p += (bytes + 255) & ~(size_t)255;
    return r;
  };
  _Float16* Xh  = (_Float16*)take((size_t)4096 * 4096 * 2);
  _Float16* Xl  = (_Float16*)take((size_t)4096 * 4096 * 2);
  _Float16* W1h = (_Float16*)take((size_t)1024 * 4096 * 2);
  _Float16* W1l = (_Float16*)take((size_t)1024 * 4096 * 2);
  _Float16* H1h = (_Float16*)take((size_t)4096 * 1024 * 2);
  _Float16* H1l = (_Float16*)take((size_t)4096 * 1024 * 2);
  _Float16* W2h = (_Float16*)take((size_t)512 * 1024 * 2);
  _Float16* W2l = (_Float16*)take((size_t)512 * 1024 * 2);
  _Float16* H2h = (_Float16*)take((size_t)4096 * 512 * 2);
  _Float16* H2l = (_Float16*)take((size_t)4096 * 512 * 2);
  _Float16* W3h = (_Float16*)take((size_t)256 * 512 * 2);
  _Float16* W3l = (_Float16*)take((size_t)256 * 512 * 2);
  _Float16* H3h = (_Float16*)take((size_t)4096 * 256 * 2);
  _Float16* H3l = (_Float16*)take((size_t)4096 * 256 * 2);
  _Float16* W4h = (_Float16*)take((size_t)256 * 256 * 2);
  _Float16* W4l = (_Float16*)take((size_t)256 * 256 * 2);
  float*    b4p = (float*)take(256 * 4);
  float*    Pp  = (float*)take((size_t)4096 * 256 * 4);

  split_x<<<16384, 256, 0, stream>>>((const float4*)X, (f16x4*)Xh, (f16x4*)Xl);
  split_weights<<<4801, 256, 0, stream>>>(W1, W2, W3, W4, b4,
                                          (f16x4*)W1h, (f16x4*)W1l, (f16x4*)W2h, (f16x4*)W2l,
                                          (f16x4*)W3h, (f16x4*)W3l, (f16x4*)W4h, (f16x4*)W4l, b4p);

  gemm_f16x2<128, 1024, 4096, true, true><<<dim3(16, 32), 256, 0, stream>>>(
      Xh, Xl, W1h, W1l, b1, H1h, H1l, nullptr);
  gemm_f16x2<64, 512, 1024, true, true><<<dim3(8, 64), 256, 0, stream>>>(
      H1h, H1l, W2h, W2l, b2, H2h, H2l, nullptr);
  gemm_f16x2<64, 256, 512, true, true><<<dim3(4, 64), 256, 0, stream>>>(
      H2h, H2l, W3h, W3l, b3, H3h, H3l, nullptr);
  gemm_f16x2<64, 256, 256, false, false><<<dim3(4, 64), 256, 0, stream>>>(
      H3h, H3l, W4h, W4l, b4p, nullptr, nullptr, Pp);

  synth<<<4096, 256, 0, stream>>>(Pp, out);
}

// Round 4
// 414.768 us; speedup vs baseline: 1.1863x; 1.1863x over previous
//
#include <hip/hip_runtime.h>

// GaborAutoencoder on MI355X (gfx950)
// split fp32 -> fp16 (hi, lo*4096) -> 3-pass split-precision MFMA GEMMs -> Gabor synth.
// R4: swizzled fragment-order LDS -- staging keeps R1's contiguous-64B global
//     pattern (4 lanes/segment) while ds_read stays conflict-free (2/bank/phase):
//       staging lane l -> row l>>2, chunk ((l&3) - (l>>3))&3, LDS slot l
//       frag read lane l' (r=l'&15,q=l'>>4) -> slot 4r + ((q + (r>>1))&3)
//     synth: contiguous-8 t per thread + per-wave 5-sigma window skip.

#define SIGNAL_LEN 2048
#define NWAV 32

typedef _Float16 f16x8 __attribute__((ext_vector_type(8)));
typedef _Float16 f16x4 __attribute__((ext_vector_type(4)));
typedef float    f32x4 __attribute__((ext_vector_type(4)));

__device__ __forceinline__ void load16_lds(const _Float16* g, _Float16* l) {
  __builtin_amdgcn_global_load_lds((const __attribute__((address_space(1))) void*)g,
                                   (__attribute__((address_space(3))) void*)l,
                                   16, 0, 0);
}

struct HL { _Float16 h, l; };
__device__ __forceinline__ HL split_one(float a) {
  HL r;
  r.h = (_Float16)a;
  r.l = (_Float16)((a - (float)r.h) * 4096.0f);
  return r;
}

// ---------------------------------------------------------------------------
// X split: fp32 float4 -> hi/lo f16x4
// ---------------------------------------------------------------------------
__global__ void split_x(const float4* __restrict__ src, f16x4* __restrict__ dh,
                        f16x4* __restrict__ dl) {
  int i = blockIdx.x * 256 + threadIdx.x;  // 4194304 float4s
  float4 v = src[i];
  float a[4] = {v.x, v.y, v.z, v.w};
  f16x4 h, l;
#pragma unroll
  for (int j = 0; j < 4; j++) {
    HL r = split_one(a[j]);
    h[j] = r.h;
    l[j] = r.l;
  }
  dh[i] = h;
  dl[i] = l;
}

// ---------------------------------------------------------------------------
// all weight splits in one launch (scaled x256); W4 padded 160x256 -> 256x256
// blocks: [0,4096) W1 | [4096,4608) W2 | [4608,4736) W3 | [4736,4800) W4 | 4800 b4
// ---------------------------------------------------------------------------
__global__ void split_weights(const float* __restrict__ W1, const float* __restrict__ W2,
                              const float* __restrict__ W3, const float* __restrict__ W4,
                              const float* __restrict__ b4,
                              f16x4* __restrict__ W1h, f16x4* __restrict__ W1l,
                              f16x4* __restrict__ W2h, f16x4* __restrict__ W2l,
                              f16x4* __restrict__ W3h, f16x4* __restrict__ W3l,
                              f16x4* __restrict__ W4h, f16x4* __restrict__ W4l,
                              float* __restrict__ b4p) {
  const int blk = blockIdx.x;
  const int tid = threadIdx.x;
  if (blk < 4736) {
    const float4* src;
    f16x4 *dh, *dl;
    int i;
    if (blk < 4096) {
      src = (const float4*)W1; dh = W1h; dl = W1l; i = blk * 256 + tid;
    } else if (blk < 4608) {
      src = (const float4*)W2; dh = W2h; dl = W2l; i = (blk - 4096) * 256 + tid;
    } else {
      src = (const float4*)W3; dh = W3h; dl = W3l; i = (blk - 4608) * 256 + tid;
    }
    float4 v = src[i];
    float a[4] = {v.x * 256.0f, v.y * 256.0f, v.z * 256.0f, v.w * 256.0f};
    f16x4 h, l;
#pragma unroll
    for (int j = 0; j < 4; j++) {
      HL r = split_one(a[j]);
      h[j] = r.h;
      l[j] = r.l;
    }
    dh[i] = h;
    dl[i] = l;
  } else if (blk < 4800) {
    int i = (blk - 4736) * 256 + tid;  // 16384 f16x4 outputs over 256x256
    int i4 = i << 2;
    int row = i4 >> 8;
    f16x4 h, l;
#pragma unroll
    for (int j = 0; j < 4; j++) {
      float a = (row < 160) ? W4[i4 + j] * 256.0f : 0.0f;
      HL r = split_one(a);
      h[j] = r.h;
      l[j] = r.l;
    }
    W4h[i] = h;
    W4l[i] = l;
  } else {
    b4p[tid] = (tid < 160) ? b4[tid] : 0.0f;
  }
}

// ---------------------------------------------------------------------------
// fp16x2 split-precision GEMM: C[M,N] = A[M,K]*B[N,K]^T (+bias, relu)
// tile TM(M) x 64(N), BK=32, 256 threads = 4 waves 2x2, 16x16x32 MFMA.
// Swizzled fragment-order LDS (see header comment): contiguous-64B staging,
// conflict-free ds_read_b128.
// ---------------------------------------------------------------------------
template <int TM, int N, int K, bool RELU, bool SPLIT_OUT>
__global__ void __launch_bounds__(256, 2)
gemm_f16x2(const _Float16* __restrict__ Ah, const _Float16* __restrict__ Al,
           const _Float16* __restrict__ Bh, const _Float16* __restrict__ Bl,
           const float* __restrict__ bias,
           _Float16* __restrict__ Ch, _Float16* __restrict__ Cl,
           float* __restrict__ Cf) {
  constexpr int IM = TM / 32;  // A fragments per wave in m
  __shared__ __align__(16) _Float16 sAh[TM * 32];
  __shared__ __align__(16) _Float16 sAl[TM * 32];
  __shared__ __align__(16) _Float16 sBh[64 * 32];
  __shared__ __align__(16) _Float16 sBl[64 * 32];

  const int tid = threadIdx.x;
  const int lane = tid & 63;
  const int w = tid >> 6;
  const int wm = w >> 1, wn = w & 1;
  const int m0 = blockIdx.y * TM;
  const int n0 = blockIdx.x * 64;

  // staging: lane l stages global (row = 16w + (l>>2), chunk ((l&3)-(l>>3))&3)
  // into LDS slot l of the wave's group => 4-lane groups cover 64 contiguous B
  const int srow = lane >> 2;
  const int schunk = ((lane & 3) - (lane >> 3)) & 3;
  const int sk8 = schunk * 8;

  const size_t aOff = (size_t)(m0 + 16 * w + srow) * K + sk8;
  const _Float16* gAh0 = Ah + aOff;
  const _Float16* gAl0 = Al + aOff;
  const size_t bOff = (size_t)(n0 + 16 * w + srow) * K + sk8;
  const _Float16* gBh0 = Bh + bOff;
  const _Float16* gBl0 = Bl + bOff;

  _Float16* lAh0 = sAh + w * 512;
  _Float16* lAl0 = sAl + w * 512;
  _Float16* lAh1 = sAh + 2048 + w * 512;  // rows 64..127 (TM=128 only)
  _Float16* lAl1 = sAl + 2048 + w * 512;
  _Float16* lBh = sBh + w * 512;
  _Float16* lBl = sBl + w * 512;

  // fragment read: lane (r=lane&15, q=lane>>4) -> group g slot 4r+((q+(r>>1))&3)
  const int fr = lane & 15;
  const int fq = lane >> 4;
  const int fslot8 = (4 * fr + ((fq + (fr >> 1)) & 3)) * 8;  // in halves

  f32x4 acc1[IM][2], acc2[IM][2];
#pragma unroll
  for (int i = 0; i < IM; i++)
#pragma unroll
    for (int j = 0; j < 2; j++) {
      acc1[i][j] = 0.0f;
      acc2[i][j] = 0.0f;
    }

  for (int kt = 0; kt < K; kt += 32) {
    load16_lds(gAh0 + kt, lAh0);
    load16_lds(gAl0 + kt, lAl0);
    if (TM == 128) {
      load16_lds(gAh0 + (size_t)64 * K + kt, lAh1);
      load16_lds(gAl0 + (size_t)64 * K + kt, lAl1);
    }
    load16_lds(gBh0 + kt, lBh);
    load16_lds(gBl0 + kt, lBl);
    __syncthreads();

    f16x8 fAh[IM], fAl[IM], fBh[2], fBl[2];
#pragma unroll
    for (int im = 0; im < IM; im++) {
      fAh[im] = *(const f16x8*)(sAh + (wm * IM + im) * 512 + fslot8);
      fAl[im] = *(const f16x8*)(sAl + (wm * IM + im) * 512 + fslot8);
    }
#pragma unroll
    for (int in = 0; in < 2; in++) {
      fBh[in] = *(const f16x8*)(sBh + (wn * 2 + in) * 512 + fslot8);
      fBl[in] = *(const f16x8*)(sBl + (wn * 2 + in) * 512 + fslot8);
    }
#pragma unroll
    for (int im = 0; im < IM; im++) {
#pragma unroll
      for (int in = 0; in < 2; in++) {
        acc1[im][in] = __builtin_amdgcn_mfma_f32_16x16x32_f16(fAh[im], fBh[in], acc1[im][in], 0, 0, 0);
        acc2[im][in] = __builtin_amdgcn_mfma_f32_16x16x32_f16(fAh[im], fBl[in], acc2[im][in], 0, 0, 0);
        acc2[im][in] = __builtin_amdgcn_mfma_f32_16x16x32_f16(fAl[im], fBh[in], acc2[im][in], 0, 0, 0);
      }
    }
    __syncthreads();
  }

  // epilogue: C/D layout col=lane&15, row=quad*4+reg
  const int quad = lane >> 4;
#pragma unroll
  for (int in = 0; in < 2; in++) {
    const int n = n0 + wn * 32 + in * 16 + fr;
    const float bv = bias[n];
#pragma unroll
    for (int im = 0; im < IM; im++) {
#pragma unroll
      for (int r = 0; r < 4; r++) {
        const int m = m0 + wm * (TM / 2) + im * 16 + quad * 4 + r;
        float c = (acc1[im][in][r] + acc2[im][in][r] * (1.0f / 4096.0f)) * (1.0f / 256.0f) + bv;
        if (RELU) c = fmaxf(c, 0.0f);
        const size_t off = (size_t)m * N + n;
        if (SPLIT_OUT) {
          HL rr = split_one(c);
          Ch[off] = rr.h;
          Cl[off] = rr.l;
        } else {
          Cf[off] = c;
        }
      }
    }
  }
}

// ---------------------------------------------------------------------------
// Gabor synthesis: one block per batch; thread owns 8 CONTIGUOUS t samples so
// each wave covers 512 contiguous samples -> per-wavelet wave-uniform 5-sigma
// window skip (envelope < 4e-6 outside).
// ---------------------------------------------------------------------------
__global__ void __launch_bounds__(256)
synth(const float* __restrict__ P, float* __restrict__ out) {
  __shared__ float sA[NWAV], sT0[NWAV], sF[NWAV], sC[NWAV], sPh[NWAV], sSg[NWAV];
  const int b = blockIdx.x;
  const int tid = threadIdx.x;
  if (tid < NWAV) {
    const float* q = P + (size_t)b * 256 + tid * 5;
    const float L2E = 1.44269504088896340736f;
    float A = q[0], p1 = q[1], p2 = q[2], p3 = q[3], p4 = q[4];
    float s1 = 1.0f / (1.0f + exp2f(-p1 * L2E));
    float s2 = 1.0f / (1.0f + exp2f(-p2 * L2E));
    float s3 = 1.0f / (1.0f + exp2f(-p3 * L2E));
    float sg = s3 * 200.0f + 2.0f;
    sA[tid] = A;
    sT0[tid] = s1 * 2048.0f;
    sF[tid] = s2 * 0.5f;
    sC[tid] = -L2E / (2.0f * sg * sg);          // exp(-dt^2/(2s^2)) = exp2(dt^2*sC)
    sPh[tid] = p4 * 0.15915494309189535f;       // phi in revolutions
    sSg[tid] = sg;
  }
  __syncthreads();

  const float t0f = (float)(tid * 8);
  const int wlo = (tid & ~63) * 8;               // wave's first t
  float acc[8];
#pragma unroll
  for (int i = 0; i < 8; i++) acc[i] = 0.0f;

  for (int wv = 0; wv < NWAV; wv++) {
    const float t0 = sT0[wv], sg = sSg[wv];
    // wave-uniform window test: wave covers [wlo, wlo+512)
    if (t0 + 5.0f * sg < (float)wlo || t0 - 5.0f * sg > (float)(wlo + 511)) continue;
    const float A = sA[wv], fr = sF[wv], cn = sC[wv], ph = sPh[wv];
#pragma unroll
    for (int i = 0; i < 8; i++) {
      float dt = (t0f + (float)i) - t0;
      float e = exp2f(dt * dt * cn);
      float r = fr * dt + ph;                    // phase in revolutions
      r -= floorf(r);                            // reduce to [0,1)
      float cs = __builtin_amdgcn_cosf(r);       // v_cos_f32: cos(2*pi*r)
      acc[i] += A * e * cs;
    }
  }

  float* o = out + (size_t)b * (2 * SIGNAL_LEN) + tid * 8;
  float4 v0 = make_float4(acc[0], acc[1], acc[2], acc[3]);
  float4 v1 = make_float4(acc[4], acc[5], acc[6], acc[7]);
  *(float4*)(o) = v0;
  *(float4*)(o + 4) = v1;
  *(float4*)(o + SIGNAL_LEN) = v0;               // channel 2 identical
  *(float4*)(o + SIGNAL_LEN + 4) = v1;
}

// ---------------------------------------------------------------------------
extern "C" void kernel_launch(void* const* d_in, const int* in_sizes, int n_in,
                              void* d_out, int out_size, void* d_ws, size_t ws_size,
                              hipStream_t stream) {
  (void)in_sizes; (void)n_in; (void)out_size; (void)ws_size;
  const float* X  = (const float*)d_in[0];
  const float* W1 = (const float*)d_in[1];
  const float* b1 = (const float*)d_in[2];
  const float* W2 = (const float*)d_in[3];
  const float* b2 = (const float*)d_in[4];
  const float* W3 = (const float*)d_in[5];
  const float* b3 = (const float*)d_in[6];
  const float* W4 = (const float*)d_in[7];
  const float* b4 = (const float*)d_in[8];
  float* out = (float*)d_out;

  char* p = (char*)d_ws;
  auto take = [&](size_t bytes) -> char* {
    char* r = p;
    p += (bytes + 255) & ~(size_t)255;
    return r;
  };
  _Float16* Xh  = (_Float16*)take((size_t)4096 * 4096 * 2);
  _Float16* Xl  = (_Float16*)take((size_t)4096 * 4096 * 2);
  _Float16* W1h = (_Float16*)take((size_t)1024 * 4096 * 2);
  _Float16* W1l = (_Float16*)take((size_t)1024 * 4096 * 2);
  _Float16* H1h = (_Float16*)take((size_t)4096 * 1024 * 2);
  _Float16* H1l = (_Float16*)take((size_t)4096 * 1024 * 2);
  _Float16* W2h = (_Float16*)take((size_t)512 * 1024 * 2);
  _Float16* W2l = (_Float16*)take((size_t)512 * 1024 * 2);
  _Float16* H2h = (_Float16*)take((size_t)4096 * 512 * 2);
  _Float16* H2l = (_Float16*)take((size_t)4096 * 512 * 2);
  _Float16* W3h = (_Float16*)take((size_t)256 * 512 * 2);
  _Float16* W3l = (_Float16*)take((size_t)256 * 512 * 2);
  _Float16* H3h = (_Float16*)take((size_t)4096 * 256 * 2);
  _Float16* H3l = (_Float16*)take((size_t)4096 * 256 * 2);
  _Float16* W4h = (_Float16*)take((size_t)256 * 256 * 2);
  _Float16* W4l = (_Float16*)take((size_t)256 * 256 * 2);
  float*    b4p = (float*)take(256 * 4);
  float*    Pp  = (float*)take((size_t)4096 * 256 * 4);

  split_x<<<16384, 256, 0, stream>>>((const float4*)X, (f16x4*)Xh, (f16x4*)Xl);
  split_weights<<<4801, 256, 0, stream>>>(W1, W2, W3, W4, b4,
                                          (f16x4*)W1h, (f16x4*)W1l, (f16x4*)W2h, (f16x4*)W2l,
                                          (f16x4*)W3h, (f16x4*)W3l, (f16x4*)W4h, (f16x4*)W4l, b4p);

  gemm_f16x2<128, 1024, 4096, true, true><<<dim3(16, 32), 256, 0, stream>>>(
      Xh, Xl, W1h, W1l, b1, H1h, H1l, nullptr);
  gemm_f16x2<64, 512, 1024, true, true><<<dim3(8, 64), 256, 0, stream>>>(
      H1h, H1l, W2h, W2l, b2, H2h, H2l, nullptr);
  gemm_f16x2<64, 256, 512, true, true><<<dim3(4, 64), 256, 0, stream>>>(
      H2h, H2l, W3h, W3l, b3, H3h, H3l, nullptr);
  gemm_f16x2<64, 256, 256, false, false><<<dim3(4, 64), 256, 0, stream>>>(
      H3h, H3l, W4h, W4l, b4p, nullptr, nullptr, Pp);

  synth<<<4096, 256, 0, stream>>>(Pp, out);
}

// Round 5
// 403.790 us; speedup vs baseline: 1.2185x; 1.0272x over previous
//
#include <hip/hip_runtime.h>

// GaborAutoencoder on MI355X (gfx950)
// split fp32 -> fp16 (hi, lo*4096) -> 3-pass split-precision MFMA GEMMs -> Gabor synth.
// R5: restructured GEMM: 64x64 wave tile (4x4 MFMA, MFMA-bound not LDS-bound),
//     explicit LDS double-buffer with one barrier/K-step and prefetch issued
//     after the barrier (staging hides under compute at 1 block/CU).
//     Verified R4 swizzle kept: staging lane l -> row l>>2, chunk ((l&3)-(l>>3))&3;
//     frag read lane (r,q) -> slot 4r+((q+(r>>1))&3). Conflict-free + coalesced.

#define SIGNAL_LEN 2048
#define NWAV 32

typedef _Float16 f16x8 __attribute__((ext_vector_type(8)));
typedef _Float16 f16x4 __attribute__((ext_vector_type(4)));
typedef float    f32x4 __attribute__((ext_vector_type(4)));

__device__ __forceinline__ void load16_lds(const _Float16* g, _Float16* l) {
  __builtin_amdgcn_global_load_lds((const __attribute__((address_space(1))) void*)g,
                                   (__attribute__((address_space(3))) void*)l,
                                   16, 0, 0);
}

struct HL { _Float16 h, l; };
__device__ __forceinline__ HL split_one(float a) {
  HL r;
  r.h = (_Float16)a;
  r.l = (_Float16)((a - (float)r.h) * 4096.0f);
  return r;
}

// ---------------------------------------------------------------------------
// X split: fp32 float4 -> hi/lo f16x4
// ---------------------------------------------------------------------------
__global__ void split_x(const float4* __restrict__ src, f16x4* __restrict__ dh,
                        f16x4* __restrict__ dl) {
  int i = blockIdx.x * 256 + threadIdx.x;  // 4194304 float4s
  float4 v = src[i];
  float a[4] = {v.x, v.y, v.z, v.w};
  f16x4 h, l;
#pragma unroll
  for (int j = 0; j < 4; j++) {
    HL r = split_one(a[j]);
    h[j] = r.h;
    l[j] = r.l;
  }
  dh[i] = h;
  dl[i] = l;
}

// ---------------------------------------------------------------------------
// all weight splits in one launch (scaled x256); W4 padded 160x256 -> 256x256
// ---------------------------------------------------------------------------
__global__ void split_weights(const float* __restrict__ W1, const float* __restrict__ W2,
                              const float* __restrict__ W3, const float* __restrict__ W4,
                              const float* __restrict__ b4,
                              f16x4* __restrict__ W1h, f16x4* __restrict__ W1l,
                              f16x4* __restrict__ W2h, f16x4* __restrict__ W2l,
                              f16x4* __restrict__ W3h, f16x4* __restrict__ W3l,
                              f16x4* __restrict__ W4h, f16x4* __restrict__ W4l,
                              float* __restrict__ b4p) {
  const int blk = blockIdx.x;
  const int tid = threadIdx.x;
  if (blk < 4736) {
    const float4* src;
    f16x4 *dh, *dl;
    int i;
    if (blk < 4096) {
      src = (const float4*)W1; dh = W1h; dl = W1l; i = blk * 256 + tid;
    } else if (blk < 4608) {
      src = (const float4*)W2; dh = W2h; dl = W2l; i = (blk - 4096) * 256 + tid;
    } else {
      src = (const float4*)W3; dh = W3h; dl = W3l; i = (blk - 4608) * 256 + tid;
    }
    float4 v = src[i];
    float a[4] = {v.x * 256.0f, v.y * 256.0f, v.z * 256.0f, v.w * 256.0f};
    f16x4 h, l;
#pragma unroll
    for (int j = 0; j < 4; j++) {
      HL r = split_one(a[j]);
      h[j] = r.h;
      l[j] = r.l;
    }
    dh[i] = h;
    dl[i] = l;
  } else if (blk < 4800) {
    int i = (blk - 4736) * 256 + tid;
    int i4 = i << 2;
    int row = i4 >> 8;
    f16x4 h, l;
#pragma unroll
    for (int j = 0; j < 4; j++) {
      float a = (row < 160) ? W4[i4 + j] * 256.0f : 0.0f;
      HL r = split_one(a);
      h[j] = r.h;
      l[j] = r.l;
    }
    W4h[i] = h;
    W4l[i] = l;
  } else {
    b4p[tid] = (tid < 160) ? b4[tid] : 0.0f;
  }
}

// ---------------------------------------------------------------------------
// fp16x2 split-precision GEMM, double-buffered.
// C[M,N] = A[M,K]*B[N,K]^T (+bias, relu). Tile TM x TN, 256 threads = 4 waves
// (2x2), wave tile (TM/2)x(TN/2) of 16x16x32 MFMAs. One barrier per K32 step.
// Unified LDS: unit u (16 rows x 32 halves of one tensor, hi or lo) at u*512
// halves; A units [0, TM/8), B units [TM/8, (TM+TN)/8).
// ---------------------------------------------------------------------------
template <int TM, int TN, int N, int K, bool RELU, bool SPLIT_OUT>
__global__ void __launch_bounds__(256, 2)
gemm_db(const _Float16* __restrict__ Ah, const _Float16* __restrict__ Al,
        const _Float16* __restrict__ Bh, const _Float16* __restrict__ Bl,
        const float* __restrict__ bias,
        _Float16* __restrict__ Ch, _Float16* __restrict__ Cl,
        float* __restrict__ Cf) {
  constexpr int AM = TM / 32;          // 16-wide m-frags per wave
  constexpr int BN = TN / 32;          // 16-wide n-frags per wave
  constexpr int AU = TM / 8;           // A staging units (group x hi/lo)
  constexpr int TU = (TM + TN) / 8;    // total units
  constexpr int UPW = TU / 4;          // units per wave
  constexpr int NK = K / 32;

  __shared__ __align__(16) _Float16 s[2][(TM + TN) * 64];

  const int tid = threadIdx.x;
  const int lane = tid & 63;
  const int w = tid >> 6;
  const int wm = w >> 1, wn = w & 1;
  const int m0 = blockIdx.y * TM;
  const int n0 = blockIdx.x * TN;

  // staging swizzle (R4-verified)
  const int srow = lane >> 2;
  const int sk8 = (((lane & 3) - (lane >> 3)) & 3) * 8;

  // per-unit global base pointers + LDS offsets (wave-uniform base)
  const _Float16* gb[UPW];
  int lo[UPW];
#pragma unroll
  for (int i = 0; i < UPW; ++i) {
    const int u = w * UPW + i;
    if (u < AU) {
      const int g = u >> 1, hl = u & 1;
      gb[i] = (hl ? Al : Ah) + (size_t)(m0 + g * 16 + srow) * K + sk8;
    } else {
      const int ub = u - AU;
      const int g = ub >> 1, hl = ub & 1;
      gb[i] = (hl ? Bl : Bh) + (size_t)(n0 + g * 16 + srow) * K + sk8;
    }
    lo[i] = u * 512;
  }

  // fragment-read swizzled lane offset (R4-verified)
  const int fr = lane & 15;
  const int fq = lane >> 4;
  const int fslot8 = (4 * fr + ((fq + (fr >> 1)) & 3)) * 8;

  f32x4 acc1[AM][BN], acc2[AM][BN];
#pragma unroll
  for (int i = 0; i < AM; i++)
#pragma unroll
    for (int j = 0; j < BN; j++) {
      acc1[i][j] = 0.0f;
      acc2[i][j] = 0.0f;
    }

  // prologue: stage k=0 into buffer 0
#pragma unroll
  for (int i = 0; i < UPW; ++i) load16_lds(gb[i], &s[0][lo[i]]);

  for (int kt = 0; kt < NK; ++kt) {
    const int cur = kt & 1;
    __syncthreads();  // drains stage(kt); protects buf(cur^1) reads from last iter

    if (kt + 1 < NK) {
      const int kofs = (kt + 1) * 32;
#pragma unroll
      for (int i = 0; i < UPW; ++i) load16_lds(gb[i] + kofs, &s[cur ^ 1][lo[i]]);
    }

    f16x8 fAh[AM], fAl[AM], fBh[BN], fBl[BN];
#pragma unroll
    for (int im = 0; im < AM; ++im) {
      const int g = wm * AM + im;
      fAh[im] = *(const f16x8*)(&s[cur][(g * 2 + 0) * 512 + fslot8]);
      fAl[im] = *(const f16x8*)(&s[cur][(g * 2 + 1) * 512 + fslot8]);
    }
#pragma unroll
    for (int in = 0; in < BN; ++in) {
      const int g = wn * BN + in;
      fBh[in] = *(const f16x8*)(&s[cur][TM * 64 + (g * 2 + 0) * 512 + fslot8]);
      fBl[in] = *(const f16x8*)(&s[cur][TM * 64 + (g * 2 + 1) * 512 + fslot8]);
    }
#pragma unroll
    for (int im = 0; im < AM; ++im) {
#pragma unroll
      for (int in = 0; in < BN; ++in) {
        acc1[im][in] = __builtin_amdgcn_mfma_f32_16x16x32_f16(fAh[im], fBh[in], acc1[im][in], 0, 0, 0);
        acc2[im][in] = __builtin_amdgcn_mfma_f32_16x16x32_f16(fAh[im], fBl[in], acc2[im][in], 0, 0, 0);
        acc2[im][in] = __builtin_amdgcn_mfma_f32_16x16x32_f16(fAl[im], fBh[in], acc2[im][in], 0, 0, 0);
      }
    }
  }

  // epilogue: C/D layout col=lane&15, row=quad*4+reg
  const int quad = lane >> 4;
#pragma unroll
  for (int in = 0; in < BN; ++in) {
    const int n = n0 + wn * (TN / 2) + in * 16 + fr;
    const float bv = bias[n];
#pragma unroll
    for (int im = 0; im < AM; ++im) {
#pragma unroll
      for (int r = 0; r < 4; ++r) {
        const int m = m0 + wm * (TM / 2) + im * 16 + quad * 4 + r;
        float c = (acc1[im][in][r] + acc2[im][in][r] * (1.0f / 4096.0f)) * (1.0f / 256.0f) + bv;
        if (RELU) c = fmaxf(c, 0.0f);
        const size_t off = (size_t)m * N + n;
        if (SPLIT_OUT) {
          HL rr = split_one(c);
          Ch[off] = rr.h;
          Cl[off] = rr.l;
        } else {
          Cf[off] = c;
        }
      }
    }
  }
}

// ---------------------------------------------------------------------------
// Gabor synthesis: one block per batch; thread owns 8 contiguous t samples,
// per-wavelet wave-uniform 5-sigma window skip.
// ---------------------------------------------------------------------------
__global__ void __launch_bounds__(256)
synth(const float* __restrict__ P, float* __restrict__ out) {
  __shared__ float sA[NWAV], sT0[NWAV], sF[NWAV], sC[NWAV], sPh[NWAV], sSg[NWAV];
  const int b = blockIdx.x;
  const int tid = threadIdx.x;
  if (tid < NWAV) {
    const float* q = P + (size_t)b * 256 + tid * 5;
    const float L2E = 1.44269504088896340736f;
    float A = q[0], p1 = q[1], p2 = q[2], p3 = q[3], p4 = q[4];
    float s1 = 1.0f / (1.0f + exp2f(-p1 * L2E));
    float s2 = 1.0f / (1.0f + exp2f(-p2 * L2E));
    float s3 = 1.0f / (1.0f + exp2f(-p3 * L2E));
    float sg = s3 * 200.0f + 2.0f;
    sA[tid] = A;
    sT0[tid] = s1 * 2048.0f;
    sF[tid] = s2 * 0.5f;
    sC[tid] = -L2E / (2.0f * sg * sg);
    sPh[tid] = p4 * 0.15915494309189535f;
    sSg[tid] = sg;
  }
  __syncthreads();

  const float t0f = (float)(tid * 8);
  const int wlo = (tid & ~63) * 8;
  float acc[8];
#pragma unroll
  for (int i = 0; i < 8; i++) acc[i] = 0.0f;

  for (int wv = 0; wv < NWAV; wv++) {
    const float t0 = sT0[wv], sg = sSg[wv];
    if (t0 + 5.0f * sg < (float)wlo || t0 - 5.0f * sg > (float)(wlo + 511)) continue;
    const float A = sA[wv], fr = sF[wv], cn = sC[wv], ph = sPh[wv];
#pragma unroll
    for (int i = 0; i < 8; i++) {
      float dt = (t0f + (float)i) - t0;
      float e = exp2f(dt * dt * cn);
      float r = fr * dt + ph;
      r -= floorf(r);
      float cs = __builtin_amdgcn_cosf(r);
      acc[i] += A * e * cs;
    }
  }

  float* o = out + (size_t)b * (2 * SIGNAL_LEN) + tid * 8;
  float4 v0 = make_float4(acc[0], acc[1], acc[2], acc[3]);
  float4 v1 = make_float4(acc[4], acc[5], acc[6], acc[7]);
  *(float4*)(o) = v0;
  *(float4*)(o + 4) = v1;
  *(float4*)(o + SIGNAL_LEN) = v0;
  *(float4*)(o + SIGNAL_LEN + 4) = v1;
}

// ---------------------------------------------------------------------------
extern "C" void kernel_launch(void* const* d_in, const int* in_sizes, int n_in,
                              void* d_out, int out_size, void* d_ws, size_t ws_size,
                              hipStream_t stream) {
  (void)in_sizes; (void)n_in; (void)out_size; (void)ws_size;
  const float* X  = (const float*)d_in[0];
  const float* W1 = (const float*)d_in[1];
  const float* b1 = (const float*)d_in[2];
  const float* W2 = (const float*)d_in[3];
  const float* b2 = (const float*)d_in[4];
  const float* W3 = (const float*)d_in[5];
  const float* b3 = (const float*)d_in[6];
  const float* W4 = (const float*)d_in[7];
  const float* b4 = (const float*)d_in[8];
  float* out = (float*)d_out;

  char* p = (char*)d_ws;
  auto take = [&](size_t bytes) -> char* {
    char* r = p;
    p += (bytes + 255) & ~(size_t)255;
    return r;
  };
  _Float16* Xh  = (_Float16*)take((size_t)4096 * 4096 * 2);
  _Float16* Xl  = (_Float16*)take((size_t)4096 * 4096 * 2);
  _Float16* W1h = (_Float16*)take((size_t)1024 * 4096 * 2);
  _Float16* W1l = (_Float16*)take((size_t)1024 * 4096 * 2);
  _Float16* H1h = (_Float16*)take((size_t)4096 * 1024 * 2);
  _Float16* H1l = (_Float16*)take((size_t)4096 * 1024 * 2);
  _Float16* W2h = (_Float16*)take((size_t)512 * 1024 * 2);
  _Float16* W2l = (_Float16*)take((size_t)512 * 1024 * 2);
  _Float16* H2h = (_Float16*)take((size_t)4096 * 512 * 2);
  _Float16* H2l = (_Float16*)take((size_t)4096 * 512 * 2);
  _Float16* W3h = (_Float16*)take((size_t)256 * 512 * 2);
  _Float16* W3l = (_Float16*)take((size_t)256 * 512 * 2);
  _Float16* H3h = (_Float16*)take((size_t)4096 * 256 * 2);
  _Float16* H3l = (_Float16*)take((size_t)4096 * 256 * 2);
  _Float16* W4h = (_Float16*)take((size_t)256 * 256 * 2);
  _Float16* W4l = (_Float16*)take((size_t)256 * 256 * 2);
  float*    b4p = (float*)take(256 * 4);
  float*    Pp  = (float*)take((size_t)4096 * 256 * 4);

  split_x<<<16384, 256, 0, stream>>>((const float4*)X, (f16x4*)Xh, (f16x4*)Xl);
  split_weights<<<4801, 256, 0, stream>>>(W1, W2, W3, W4, b4,
                                          (f16x4*)W1h, (f16x4*)W1l, (f16x4*)W2h, (f16x4*)W2l,
                                          (f16x4*)W3h, (f16x4*)W3l, (f16x4*)W4h, (f16x4*)W4l, b4p);

  // grids: all 256 blocks = 1 block/CU, 4 waves, double-buffered
  gemm_db<128, 128, 1024, 4096, true, true><<<dim3(8, 32), 256, 0, stream>>>(
      Xh, Xl, W1h, W1l, b1, H1h, H1l, nullptr);
  gemm_db<64, 128, 512, 1024, true, true><<<dim3(4, 64), 256, 0, stream>>>(
      H1h, H1l, W2h, W2l, b2, H2h, H2l, nullptr);
  gemm_db<64, 64, 256, 512, true, true><<<dim3(4, 64), 256, 0, stream>>>(
      H2h, H2l, W3h, W3l, b3, H3h, H3l, nullptr);
  gemm_db<64, 64, 256, 256, false, false><<<dim3(4, 64), 256, 0, stream>>>(
      H3h, H3l, W4h, W4l, b4p, nullptr, nullptr, Pp);

  synth<<<4096, 256, 0, stream>>>(Pp, out);
}